// Round 8
// baseline (572.905 us; speedup 1.0000x reference)
//
#include <hip/hip_runtime.h>
#include <hip/hip_bf16.h>
#include <cstdint>
#include <cstddef>

// SNN: B=16384, D_IN=512, H0=1024, H1=512, T=8
// out[i] = b3 + (1/8) * sum_n w3[n] * popcount(spk2_pattern[i][n])
//
// NUMERICS FROZEN at the round-3 passing configuration (absmax 3.234863e-3):
//  - K1: f32 VALU GEMM, per-element fmaf chain in strict k=0..511 order.
//  - K2: MFMA, A = spike bits -> bf16 {0,1} via v_perm, B = w2 pre-split
//        hi/mid/lo bf16, 3 MFMAs/frag in hi,mid,lo order per acc chain.
// The absmax gate is a spike-flip lottery (threshold < max|w3|/8): any
// numeric deviation re-rolls the dice. Structure-only changes allowed.
//
// Round 8 structure change (bit-exact): K2 t-SPLIT ACROSS WAVES.
//  512 thr / 8 waves: wave (tg=wv>>2, ig=wv&3) owns time steps tg*4..tg*4+3
//  for i-rows ig*16..+16. acc shrinks 128->64 regs/wave -> ~160 unified ->
//  3 waves/SIMD (was 2). Each acc[t][nf] sees the identical kb->s->(h,m,l)
//  MFMA sequence -> bit-identical. Epilogue: tg=1 waves hand their acc to
//  tg=0 via the dead 64KB LDS; tg=0 runs the exact 8-step LIF chain.
//  K1 untouched from round 7.

#define NB 16384
#define DIN 512
#define NH0 1024
#define NH1 512

typedef float f32x4 __attribute__((ext_vector_type(4)));
typedef short bf16x8 __attribute__((ext_vector_type(8)));

// d_ws layout (bytes)
#define WS_PAT   0u
#define WS_W2H   19922944u
#define WS_W2M   20971520u
#define WS_W2L   22020096u

__device__ inline uint16_t f2bf(float f) {
    __hip_bfloat16 h = __float2bfloat16(f);
    return *reinterpret_cast<uint16_t*>(&h);
}
__device__ inline float bf2f(uint16_t u) {
    __hip_bfloat16 h = *reinterpret_cast<__hip_bfloat16*>(&u);
    return __bfloat162float(h);
}

__global__ void init_out_kernel(float* __restrict__ out,
                                const float* __restrict__ b3, int n) {
    int i = blockIdx.x * blockDim.x + threadIdx.x;
    if (i < n) out[i] = b3[0];
}

// ---------------- split3: f32 -> bf16 hi/mid/lo (elementwise) ----------------
__global__ __launch_bounds__(256) void split3_kernel(
    const float* __restrict__ src, uint16_t* __restrict__ h,
    uint16_t* __restrict__ m, uint16_t* __restrict__ l, int n)
{
    int i = (blockIdx.x * 256 + threadIdx.x) * 4;
    if (i >= n) return;
    float4 f = *(const float4*)(src + i);
    float fv[4] = {f.x, f.y, f.z, f.w};
    uint32_t hw[2], mw[2], lw[2];
    #pragma unroll
    for (int g = 0; g < 2; ++g) {
        uint16_t hh[2], mm[2], ll[2];
        #pragma unroll
        for (int e = 0; e < 2; ++e) {
            float a = fv[2 * g + e];
            uint16_t h0 = f2bf(a);
            float d = __fsub_rn(a, bf2f(h0));
            uint16_t m0 = f2bf(d);
            float e2 = __fsub_rn(d, bf2f(m0));
            uint16_t l0 = f2bf(e2);
            hh[e] = h0; mm[e] = m0; ll[e] = l0;
        }
        hw[g] = (uint32_t)hh[0] | ((uint32_t)hh[1] << 16);
        mw[g] = (uint32_t)mm[0] | ((uint32_t)mm[1] << 16);
        lw[g] = (uint32_t)ll[0] | ((uint32_t)ll[1] << 16);
    }
    *(uint2*)(h + i) = make_uint2(hw[0], hw[1]);
    *(uint2*)(m + i) = make_uint2(mw[0], mw[1]);
    *(uint2*)(l + i) = make_uint2(lw[0], lw[1]);
}

// - K1: f32 VALU GEMM1 + LIF1, 512 thr, 128x128 tile, 8x4/thread, bit-exact -
__global__ __launch_bounds__(512, 4) void gemm1_spike_kernel(
    const float* __restrict__ data, const float* __restrict__ w1,
    const float* __restrict__ b1, uint8_t* __restrict__ pat)
{
    __shared__ float As[128][68];
    __shared__ float Bs[128][68];
    const int tid = threadIdx.x;
    const int tx = tid & 31;
    const int ty = tid >> 5;
    const int i0 = blockIdx.x * 128, n0 = blockIdx.y * 128;

    float acc[8][4] = {};

    for (int kb = 0; kb < DIN; kb += 64) {
        #pragma unroll
        for (int rep = 0; rep < 4; ++rep) {
            int idx = tid + rep * 512;
            int row = idx >> 4, c4 = (idx & 15) * 4;
            *(float4*)(&As[row][c4]) =
                *(const float4*)(data + (size_t)(i0 + row) * DIN + kb + c4);
            *(float4*)(&Bs[row][c4]) =
                *(const float4*)(w1 + (size_t)(n0 + row) * DIN + kb + c4);
        }
        __syncthreads();
        #pragma unroll 2
        for (int k4 = 0; k4 < 16; ++k4) {
            float4 a4[8], b4[4];
            #pragma unroll
            for (int ii = 0; ii < 8; ++ii)
                a4[ii] = *(const float4*)(&As[ty + ii * 16][k4 * 4]);
            #pragma unroll
            for (int nn = 0; nn < 4; ++nn)
                b4[nn] = *(const float4*)(&Bs[tx + nn * 32][k4 * 4]);
            #pragma unroll
            for (int ii = 0; ii < 8; ++ii) {
                #pragma unroll
                for (int nn = 0; nn < 4; ++nn) {
                    acc[ii][nn] = fmaf(a4[ii].x, b4[nn].x, acc[ii][nn]);
                    acc[ii][nn] = fmaf(a4[ii].y, b4[nn].y, acc[ii][nn]);
                    acc[ii][nn] = fmaf(a4[ii].z, b4[nn].z, acc[ii][nn]);
                    acc[ii][nn] = fmaf(a4[ii].w, b4[nn].w, acc[ii][nn]);
                }
            }
        }
        __syncthreads();
    }

    #pragma unroll
    for (int ii = 0; ii < 8; ++ii) {
        const int i = i0 + ty + ii * 16;
        #pragma unroll
        for (int nn = 0; nn < 4; ++nn) {
            const int n = n0 + tx + nn * 32;
            float x = __fadd_rn(acc[ii][nn], b1[n]);
            float mem = 0.0f;
            unsigned p = 0;
            #pragma unroll
            for (int t = 0; t < 8; ++t) {
                bool reset = mem > 1.0f;
                float tmp = __fadd_rn(mem, x);
                mem = reset ? __fsub_rn(tmp, 1.0f) : tmp;
                p |= (mem > 1.0f ? 1u : 0u) << t;
            }
            pat[(size_t)(n >> 6) * (NB * 64) + (size_t)i * 64 + (n & 63)] = (uint8_t)p;
        }
    }
}

// -- K2: MFMA 8x GEMM, 512 thr, t-split across waves, dbuf + async-stage ----
__global__ __launch_bounds__(512, 3) void gemm2_mfma_kernel(
    const uint8_t* __restrict__ pat,
    const uint16_t* __restrict__ w2h, const uint16_t* __restrict__ w2m,
    const uint16_t* __restrict__ w2l,
    const float* __restrict__ b2, const float* __restrict__ w3,
    float* __restrict__ out)
{
    __shared__ __align__(16) uint8_t lds_raw[65536];
    uint16_t* Bh_ = (uint16_t*)lds_raw;              // [2][64][72] u16
    uint16_t* Bm_ = (uint16_t*)(lds_raw + 18432);
    uint16_t* Bl_ = (uint16_t*)(lds_raw + 36864);
    uint8_t*  Ap_ = lds_raw + 55296;                 // [2][64][80] u8

    const int tid  = threadIdx.x;
    const int lane = tid & 63;
    const int wv   = tid >> 6;       // 0..7
    const int tg   = wv >> 2;        // 0: t=0..3, 1: t=4..7
    const int ig   = wv & 3;         // i-row group
    const int lr   = lane & 15;
    const int lg   = lane >> 4;
    const int i0   = blockIdx.x * 64, n0 = blockIdx.y * 64;

    f32x4 acc[4][4];                 // [tloc][nf]
    #pragma unroll
    for (int tl = 0; tl < 4; ++tl)
        #pragma unroll
        for (int nf = 0; nf < 4; ++nf)
            acc[tl][nf] = (f32x4)(0.0f);

    // staging map: 512 threads, 1 uint4 per split buffer + Ap for tid<256
    const int srow = tid >> 3;             // 0..63
    const int sc8  = (tid & 7) * 8;        // u16 offset 0..56
    const size_t wbase = (size_t)(n0 + srow) * NH0 + sc8;
    const size_t pbase = (size_t)i0 * 64 + (size_t)tid * 16;

    uint4 rh, rm, rl, rp;

    // prologue: stage tile 0 into buffer 0
    {
        rh = *(const uint4*)(w2h + wbase);
        rm = *(const uint4*)(w2m + wbase);
        rl = *(const uint4*)(w2l + wbase);
        *(uint4*)(Bh_ + srow * 72 + sc8) = rh;
        *(uint4*)(Bm_ + srow * 72 + sc8) = rm;
        *(uint4*)(Bl_ + srow * 72 + sc8) = rl;
        if (tid < 256) {
            rp = *(const uint4*)(pat + pbase);
            *(uint4*)(Ap_ + (tid >> 2) * 80 + (tid & 3) * 16) = rp;
        }
    }

    int cur = 0;
    for (int kbi = 0; kbi < 16; ++kbi) {
        __syncthreads();   // buf[cur] ready; buf[cur^1] free
        if (kbi < 15) {
            const int kb = (kbi + 1) * 64;
            rh = *(const uint4*)(w2h + wbase + kb);
            rm = *(const uint4*)(w2m + wbase + kb);
            rl = *(const uint4*)(w2l + wbase + kb);
            if (tid < 256)
                rp = *(const uint4*)(pat + (size_t)(kbi + 1) * (NB * 64) + pbase);
        }

        // ---- compute tile kbi from buf[cur] (per-acc MFMA order frozen) ----
        #pragma unroll
        for (int s = 0; s < 2; ++s) {
            const int k0 = s * 32;
            bf16x8 bh[4], bm[4], bl[4];
            #pragma unroll
            for (int nf = 0; nf < 4; ++nf) {
                const int col = nf * 16 + lr;
                bh[nf] = *(const bf16x8*)(Bh_ + (size_t)cur * 4608 + col * 72 + k0 + lg * 8);
                bm[nf] = *(const bf16x8*)(Bm_ + (size_t)cur * 4608 + col * 72 + k0 + lg * 8);
                bl[nf] = *(const bf16x8*)(Bl_ + (size_t)cur * 4608 + col * 72 + k0 + lg * 8);
            }
            const uint2 p8 = *(const uint2*)(Ap_ + (size_t)cur * 5120 +
                                             (ig * 16 + lr) * 80 + k0 + lg * 8);
            #pragma unroll
            for (int tl = 0; tl < 4; ++tl) {
                const int t = tg * 4 + tl;
                uint32_t y0 = (p8.x >> t) & 0x01010101u;
                uint32_t y1 = (p8.y >> t) & 0x01010101u;
                uint32_t s0 = __builtin_amdgcn_perm(0u, y0, 0x01010000u) | 0x02000200u;
                uint32_t s1x = __builtin_amdgcn_perm(0u, y0, 0x03030202u) | 0x02000200u;
                uint32_t s2x = __builtin_amdgcn_perm(0u, y1, 0x01010000u) | 0x02000200u;
                uint32_t s3x = __builtin_amdgcn_perm(0u, y1, 0x03030202u) | 0x02000200u;
                union { uint4 u; bf16x8 v; } af;
                af.u = make_uint4(__builtin_amdgcn_perm(0u, 0x3F008000u, s0),
                                  __builtin_amdgcn_perm(0u, 0x3F008000u, s1x),
                                  __builtin_amdgcn_perm(0u, 0x3F008000u, s2x),
                                  __builtin_amdgcn_perm(0u, 0x3F008000u, s3x));
                #pragma unroll
                for (int nf = 0; nf < 4; ++nf) {
                    acc[tl][nf] = __builtin_amdgcn_mfma_f32_16x16x32_bf16(
                        af.v, bh[nf], acc[tl][nf], 0, 0, 0);
                    acc[tl][nf] = __builtin_amdgcn_mfma_f32_16x16x32_bf16(
                        af.v, bm[nf], acc[tl][nf], 0, 0, 0);
                    acc[tl][nf] = __builtin_amdgcn_mfma_f32_16x16x32_bf16(
                        af.v, bl[nf], acc[tl][nf], 0, 0, 0);
                }
            }
        }

        if (kbi < 15) {
            const int nb = cur ^ 1;
            *(uint4*)(Bh_ + (size_t)nb * 4608 + srow * 72 + sc8) = rh;
            *(uint4*)(Bm_ + (size_t)nb * 4608 + srow * 72 + sc8) = rm;
            *(uint4*)(Bl_ + (size_t)nb * 4608 + srow * 72 + sc8) = rl;
            if (tid < 256)
                *(uint4*)(Ap_ + (size_t)nb * 5120 + (tid >> 2) * 80 + (tid & 3) * 16) = rp;
        }
        cur ^= 1;
    }

    // ---- cross-wave t-handoff through (dead) LDS, then exact LIF2 chain ----
    __syncthreads();
    float* xf = (float*)lds_raw;         // [64 j][256 widx]
    const int widx = ig * 64 + lane;
    if (tg == 1) {
        #pragma unroll
        for (int tl = 0; tl < 4; ++tl)
            #pragma unroll
            for (int nf = 0; nf < 4; ++nf)
                #pragma unroll
                for (int r = 0; r < 4; ++r)
                    xf[(tl * 16 + nf * 4 + r) * 256 + widx] = acc[tl][nf][r];
    }
    __syncthreads();
    if (tg == 0) {
        float rowsum[4] = {0.0f, 0.0f, 0.0f, 0.0f};
        #pragma unroll
        for (int nf = 0; nf < 4; ++nf) {
            const int n = n0 + nf * 16 + lr;
            const float b2n = b2[n];
            const float w3n = w3[n];
            #pragma unroll
            for (int r = 0; r < 4; ++r) {
                float hi4[4];
                #pragma unroll
                for (int tl = 0; tl < 4; ++tl)
                    hi4[tl] = xf[(tl * 16 + nf * 4 + r) * 256 + widx];
                float mem = 0.0f;
                int pc = 0;
                #pragma unroll
                for (int t = 0; t < 8; ++t) {
                    bool reset = mem > 1.0f;
                    float aval = (t < 4) ? acc[t][nf][r] : hi4[t - 4];
                    float x   = __fadd_rn(aval, b2n);
                    float tmp = __fadd_rn(__fmul_rn(0.95f, mem), x);
                    mem = reset ? __fsub_rn(tmp, 1.0f) : tmp;
                    pc += (mem > 1.0f) ? 1 : 0;
                }
                rowsum[r] = fmaf(w3n, (float)pc, rowsum[r]);
            }
        }
        #pragma unroll
        for (int r = 0; r < 4; ++r) {
            float s = rowsum[r];
            s += __shfl_xor(s, 1);
            s += __shfl_xor(s, 2);
            s += __shfl_xor(s, 4);
            s += __shfl_xor(s, 8);
            if (lr == 0)
                atomicAdd(&out[i0 + ig * 16 + lg * 4 + r], 0.125f * s);
        }
    }
}

extern "C" void kernel_launch(void* const* d_in, const int* in_sizes, int n_in,
                              void* d_out, int out_size, void* d_ws, size_t ws_size,
                              hipStream_t stream) {
    const float* data = (const float*)d_in[0];
    const float* w1   = (const float*)d_in[1];
    const float* b1   = (const float*)d_in[2];
    const float* w2   = (const float*)d_in[3];
    const float* b2   = (const float*)d_in[4];
    const float* w3   = (const float*)d_in[5];
    const float* b3   = (const float*)d_in[6];
    float* out = (float*)d_out;

    char* ws = (char*)d_ws;
    uint8_t*  pat = (uint8_t*)(ws + WS_PAT);   // blocked [16][16384][64]
    uint16_t* w2h = (uint16_t*)(ws + WS_W2H);
    uint16_t* w2m = (uint16_t*)(ws + WS_W2M);
    uint16_t* w2l = (uint16_t*)(ws + WS_W2L);

    init_out_kernel<<<(NB + 255) / 256, 256, 0, stream>>>(out, b3, NB);
    split3_kernel<<<(NH1 * NH0 / 4 + 255) / 256, 256, 0, stream>>>(w2, w2h, w2m, w2l, NH1 * NH0);
    gemm1_spike_kernel<<<dim3(NB / 128, NH0 / 128), 512, 0, stream>>>(data, w1, b1, pat);
    gemm2_mfma_kernel<<<dim3(NB / 64, NH1 / 64), 512, 0, stream>>>(pat, w2h, w2m, w2l, b2, w3, out);
}